// Round 1
// baseline (2389.564 us; speedup 1.0000x reference)
//
#include <hip/hip_runtime.h>
#include <stdint.h>

#define D_MODEL 1024
#define D_FF    4096
#define NE      8
#define NTOK    8192
#define CAP     1280
#define RPE     2560           // rows per expert = 2*CAP (k=0 segment + k=1 segment)
#define RTOT    (NE*RPE)       // 20480
#define TM      128
#define TN      128
#define BK      64
#define SK      (BK+8)         // LDS row stride (+16B pad -> bank stride 4 -> <=2-way, free)

typedef __attribute__((ext_vector_type(8))) short s8v;   // 8 x bf16 bits (4 VGPRs)
typedef __attribute__((ext_vector_type(4))) float f4v;   // MFMA accumulator

// fp32 -> bf16 round-to-nearest-even (finite inputs only)
__device__ inline unsigned short f2bf(float f) {
    unsigned int u = __float_as_uint(f);
    u += 0x7fffu + ((u >> 16) & 1u);
    return (unsigned short)(u >> 16);
}

// ---------------- weight fp32 -> bf16 conversion ----------------
__global__ __launch_bounds__(256) void cvt_kernel(const float* __restrict__ src,
                                                  unsigned short* __restrict__ dst, int n4) {
    int i = blockIdx.x * blockDim.x + threadIdx.x;
    int stride = gridDim.x * blockDim.x;
    for (; i < n4; i += stride) {
        float4 v = ((const float4*)src)[i];
        union { unsigned short us[4]; uint2 u2; } cv;
        cv.us[0] = f2bf(v.x); cv.us[1] = f2bf(v.y);
        cv.us[2] = f2bf(v.z); cv.us[3] = f2bf(v.w);
        ((uint2*)dst)[i] = cv.u2;
    }
}

// ---------------- router: fp64 logits, top-2, prob sums ----------------
__global__ __launch_bounds__(256) void router_kernel(const float* __restrict__ x,
                                                     const float* __restrict__ gate,
                                                     int* __restrict__ e0a, int* __restrict__ e1a,
                                                     float* __restrict__ w0a, float* __restrict__ w1a,
                                                     float* __restrict__ probsum) {
    __shared__ float gs[NE * D_MODEL];   // 32 KB
    int tid = threadIdx.x;
    for (int i = tid; i < NE * D_MODEL; i += 256) gs[i] = gate[i];
    __syncthreads();
    int wv = tid >> 6, lane = tid & 63;
    int t = blockIdx.x * 4 + wv;
    const float* xr = x + (size_t)t * D_MODEL;
    double acc[NE];
    #pragma unroll
    for (int e = 0; e < NE; e++) acc[e] = 0.0;
    #pragma unroll
    for (int j = 0; j < 16; j++) {
        int d = lane + 64 * j;
        double xv = (double)xr[d];
        #pragma unroll
        for (int e = 0; e < NE; e++) acc[e] += xv * (double)gs[e * D_MODEL + d];
    }
    #pragma unroll
    for (int e = 0; e < NE; e++) {
        #pragma unroll
        for (int off = 32; off > 0; off >>= 1) acc[e] += __shfl_xor(acc[e], off);
    }
    if (lane == 0) {
        double mx = acc[0];
        #pragma unroll
        for (int e = 1; e < NE; e++) mx = fmax(mx, acc[e]);
        double p[NE], s = 0.0;
        #pragma unroll
        for (int e = 0; e < NE; e++) { p[e] = exp(acc[e] - mx); s += p[e]; }
        float p32[NE];
        #pragma unroll
        for (int e = 0; e < NE; e++) p32[e] = (float)(p[e] / s);
        int b0 = 0;
        #pragma unroll
        for (int e = 1; e < NE; e++) if (p32[e] > p32[b0]) b0 = e;   // strict > => lowest idx on tie
        int b1 = (b0 == 0) ? 1 : 0;
        #pragma unroll
        for (int e = 0; e < NE; e++) if (e != b0 && p32[e] > p32[b1]) b1 = e;
        float denom = p32[b0] + p32[b1] + 1e-10f;
        e0a[t] = b0; e1a[t] = b1;
        w0a[t] = p32[b0] / denom;
        w1a[t] = p32[b1] / denom;
        #pragma unroll
        for (int e = 0; e < NE; e++) atomicAdd(&probsum[e], p32[e]);
    }
}

// ---------------- per-expert ordered capacity scan ----------------
__global__ __launch_bounds__(512) void scan_kernel(const int* __restrict__ e0a, const int* __restrict__ e1a,
                                                   const float* __restrict__ w0a, const float* __restrict__ w1a,
                                                   int* __restrict__ tok, float* __restrict__ wl,
                                                   int* __restrict__ M, int* __restrict__ counts) {
    int e = threadIdx.x >> 6;       // 8 waves, one per expert
    int lane = threadIdx.x & 63;
    unsigned long long below = (1ull << lane) - 1ull;
    int c = 0;
    for (int base = 0; base < NTOK; base += 64) {          // k = 0
        int t = base + lane;
        bool m = (e0a[t] == e);
        unsigned long long mask = __ballot(m);
        int pos = c + __popcll(mask & below);
        if (m && pos < CAP) { tok[e * RPE + pos] = t; wl[e * RPE + pos] = w0a[t]; }
        c += __popcll(mask);
    }
    int c0 = c;
    int base0 = (c0 < CAP) ? c0 : CAP;
    c = 0;
    for (int base = 0; base < NTOK; base += 64) {          // k = 1
        int t = base + lane;
        bool m = (e1a[t] == e);
        unsigned long long mask = __ballot(m);
        int pos = c + __popcll(mask & below);
        if (m && pos < CAP) { tok[e * RPE + base0 + pos] = t; wl[e * RPE + base0 + pos] = w1a[t]; }
        c += __popcll(mask);
    }
    int c1 = c;
    if (lane == 0) {
        M[e] = base0 + ((c1 < CAP) ? c1 : CAP);
        counts[e] = c0 + c1;          // pre-capacity counts, per reference
    }
}

// ---------------- gather x rows -> zero-padded bf16 buffer ----------------
__global__ __launch_bounds__(256) void gather_kernel(const float* __restrict__ x,
                                                     const int* __restrict__ tok,
                                                     const int* __restrict__ M,
                                                     unsigned short* __restrict__ Xg) {
    int wv = threadIdx.x >> 6, lane = threadIdx.x & 63;
    int r = blockIdx.x * 4 + wv;              // 0..RTOT-1
    int e = r / RPE;
    int i = r - e * RPE;
    unsigned short* dst = Xg + (size_t)r * D_MODEL;
    if (i < M[e]) {
        int t = tok[r];
        const float4* src = (const float4*)(x + (size_t)t * D_MODEL);
        #pragma unroll
        for (int j = 0; j < 4; j++) {
            float4 v = src[lane + 64 * j];
            union { unsigned short us[4]; uint2 u2; } cv;
            cv.us[0] = f2bf(v.x); cv.us[1] = f2bf(v.y);
            cv.us[2] = f2bf(v.z); cv.us[3] = f2bf(v.w);
            *(uint2*)(dst + (size_t)(lane + 64 * j) * 4) = cv.u2;
        }
    } else {
        uint2 z; z.x = 0u; z.y = 0u;
        #pragma unroll
        for (int j = 0; j < 4; j++) *(uint2*)(dst + (size_t)(lane + 64 * j) * 4) = z;
    }
}

// ---------------- GEMM1: H = silu(Xg W1^T) * (Xg W3^T), bf16 out ----------------
__global__ __launch_bounds__(256) void gemm1_kernel(const unsigned short* __restrict__ Xg,
                                                    const unsigned short* __restrict__ Wb1,
                                                    const unsigned short* __restrict__ Wb3,
                                                    unsigned short* __restrict__ H) {
    __shared__ __align__(16) unsigned short As[TM * SK];
    __shared__ __align__(16) unsigned short B1s[TN * SK];
    __shared__ __align__(16) unsigned short B3s[TN * SK];
    int bx = blockIdx.x;
    int e = bx / 640;                 // 640 = 32 n-tiles * 20 m-tiles
    int r = bx - e * 640;
    int nt = r / 20;                  // mt fastest: B-strips shared by consecutive blocks
    int mt = r - nt * 20;
    const unsigned short* Ab = Xg + ((size_t)e * RPE + (size_t)mt * TM) * D_MODEL;
    const unsigned short* B1b = Wb1 + (size_t)e * D_FF * D_MODEL + (size_t)nt * TN * D_MODEL;
    const unsigned short* B3b = Wb3 + (size_t)e * D_FF * D_MODEL + (size_t)nt * TN * D_MODEL;
    int tid = threadIdx.x;
    int lane = tid & 63, wv = tid >> 6;
    int wm = wv & 1, wn = wv >> 1;
    int quad = lane >> 4, l16 = lane & 15;
    f4v acc1[4][4], acc3[4][4];
    #pragma unroll
    for (int i = 0; i < 4; i++)
        #pragma unroll
        for (int j = 0; j < 4; j++) { acc1[i][j] = 0.0f; acc3[i][j] = 0.0f; }

    for (int kt = 0; kt < D_MODEL / BK; kt++) {
        int kof = kt * BK;
        s8v va[4], v1[4], v3[4];
        #pragma unroll
        for (int c = 0; c < 4; c++) {
            int chunk = c * 256 + tid;
            int row = chunk >> 3;
            int col = (chunk & 7) * 8;
            va[c] = *(const s8v*)(Ab  + (size_t)row * D_MODEL + kof + col);
            v1[c] = *(const s8v*)(B1b + (size_t)row * D_MODEL + kof + col);
            v3[c] = *(const s8v*)(B3b + (size_t)row * D_MODEL + kof + col);
        }
        __syncthreads();
        #pragma unroll
        for (int c = 0; c < 4; c++) {
            int chunk = c * 256 + tid;
            int row = chunk >> 3;
            int col = (chunk & 7) * 8;
            *(s8v*)(As  + row * SK + col) = va[c];
            *(s8v*)(B1s + row * SK + col) = v1[c];
            *(s8v*)(B3s + row * SK + col) = v3[c];
        }
        __syncthreads();
        #pragma unroll
        for (int st = 0; st < 2; st++) {
            s8v af[4], bf1[4], bf3[4];
            #pragma unroll
            for (int i = 0; i < 4; i++)
                af[i] = *(const s8v*)(As + (wm * 64 + i * 16 + l16) * SK + st * 32 + quad * 8);
            #pragma unroll
            for (int j = 0; j < 4; j++) {
                bf1[j] = *(const s8v*)(B1s + (wn * 64 + j * 16 + l16) * SK + st * 32 + quad * 8);
                bf3[j] = *(const s8v*)(B3s + (wn * 64 + j * 16 + l16) * SK + st * 32 + quad * 8);
            }
            #pragma unroll
            for (int i = 0; i < 4; i++)
                #pragma unroll
                for (int j = 0; j < 4; j++) {
                    acc1[i][j] = __builtin_amdgcn_mfma_f32_16x16x32_bf16(af[i], bf1[j], acc1[i][j], 0, 0, 0);
                    acc3[i][j] = __builtin_amdgcn_mfma_f32_16x16x32_bf16(af[i], bf3[j], acc3[i][j], 0, 0, 0);
                }
        }
    }
    size_t rowbase = (size_t)e * RPE + (size_t)mt * TM;
    #pragma unroll
    for (int i = 0; i < 4; i++) {
        #pragma unroll
        for (int j = 0; j < 4; j++) {
            int col = nt * TN + wn * 64 + j * 16 + l16;
            #pragma unroll
            for (int rg = 0; rg < 4; rg++) {
                int row = wm * 64 + i * 16 + quad * 4 + rg;   // C/D: col=lane&15, row=quad*4+reg
                float z = acc1[i][j][rg];
                float sg = z / (1.0f + __expf(-z));           // silu
                float h = sg * acc3[i][j][rg];
                H[(rowbase + row) * (size_t)D_FF + col] = f2bf(h);
            }
        }
    }
}

// ---------------- GEMM2: OUT = H W2^T, weighted scatter-add ----------------
__global__ __launch_bounds__(256) void gemm2_kernel(const unsigned short* __restrict__ H,
                                                    const unsigned short* __restrict__ Wb2,
                                                    const int* __restrict__ tok,
                                                    const float* __restrict__ wl,
                                                    const int* __restrict__ M,
                                                    float* __restrict__ out) {
    __shared__ __align__(16) unsigned short As[TM * SK];
    __shared__ __align__(16) unsigned short Bs[TN * SK];
    __shared__ int   tok_s[TM];
    __shared__ float wl_s[TM];
    int bx = blockIdx.x;
    int e = bx / 160;                 // 160 = 20 m-tiles * 8 n-tiles
    int r = bx - e * 160;
    int mt = r >> 3;                  // nt fastest: A-tile shared by consecutive blocks
    int nt = r & 7;
    const unsigned short* Ab = H + ((size_t)e * RPE + (size_t)mt * TM) * D_FF;
    const unsigned short* Bb = Wb2 + (size_t)e * D_MODEL * D_FF + (size_t)nt * TN * D_FF;
    int tid = threadIdx.x;
    if (tid < TM) {
        tok_s[tid] = tok[e * RPE + mt * TM + tid];
        wl_s[tid]  = wl[e * RPE + mt * TM + tid];
    }
    int Me = M[e];
    int lane = tid & 63, wv = tid >> 6;
    int wm = wv & 1, wn = wv >> 1;
    int quad = lane >> 4, l16 = lane & 15;
    f4v acc[4][4];
    #pragma unroll
    for (int i = 0; i < 4; i++)
        #pragma unroll
        for (int j = 0; j < 4; j++) acc[i][j] = 0.0f;

    for (int kt = 0; kt < D_FF / BK; kt++) {
        int kof = kt * BK;
        s8v va[4], vb[4];
        #pragma unroll
        for (int c = 0; c < 4; c++) {
            int chunk = c * 256 + tid;
            int row = chunk >> 3;
            int col = (chunk & 7) * 8;
            va[c] = *(const s8v*)(Ab + (size_t)row * D_FF + kof + col);
            vb[c] = *(const s8v*)(Bb + (size_t)row * D_FF + kof + col);
        }
        __syncthreads();
        #pragma unroll
        for (int c = 0; c < 4; c++) {
            int chunk = c * 256 + tid;
            int row = chunk >> 3;
            int col = (chunk & 7) * 8;
            *(s8v*)(As + row * SK + col) = va[c];
            *(s8v*)(Bs + row * SK + col) = vb[c];
        }
        __syncthreads();
        #pragma unroll
        for (int st = 0; st < 2; st++) {
            s8v af[4], bf[4];
            #pragma unroll
            for (int i = 0; i < 4; i++)
                af[i] = *(const s8v*)(As + (wm * 64 + i * 16 + l16) * SK + st * 32 + quad * 8);
            #pragma unroll
            for (int j = 0; j < 4; j++)
                bf[j] = *(const s8v*)(Bs + (wn * 64 + j * 16 + l16) * SK + st * 32 + quad * 8);
            #pragma unroll
            for (int i = 0; i < 4; i++)
                #pragma unroll
                for (int j = 0; j < 4; j++)
                    acc[i][j] = __builtin_amdgcn_mfma_f32_16x16x32_bf16(af[i], bf[j], acc[i][j], 0, 0, 0);
        }
    }
    int mbase = mt * TM;
    #pragma unroll
    for (int i = 0; i < 4; i++) {
        #pragma unroll
        for (int j = 0; j < 4; j++) {
            int col = nt * TN + wn * 64 + j * 16 + l16;
            #pragma unroll
            for (int rg = 0; rg < 4; rg++) {
                int row = wm * 64 + i * 16 + quad * 4 + rg;
                if (mbase + row < Me) {
                    float v = acc[i][j][rg] * wl_s[row];
                    atomicAdd(out + (size_t)tok_s[row] * D_MODEL + col, v);
                }
            }
        }
    }
}

// ---------------- aux loss finisher ----------------
__global__ void aux_kernel(const int* __restrict__ counts, const float* __restrict__ probsum,
                           float* __restrict__ out_aux) {
    if (threadIdx.x == 0 && blockIdx.x == 0) {
        float s = 0.0f;
        for (int e = 0; e < NE; e++) {
            float f = (float)counts[e] / (float)(NTOK * 2);
            float P = probsum[e] / (float)NTOK;
            s += f * P;
        }
        *out_aux = (float)NE * s;
    }
}

extern "C" void kernel_launch(void* const* d_in, const int* in_sizes, int n_in,
                              void* d_out, int out_size, void* d_ws, size_t ws_size,
                              hipStream_t stream) {
    (void)in_sizes; (void)n_in; (void)ws_size;
    const float* x    = (const float*)d_in[0];
    const float* gate = (const float*)d_in[1];
    const float* w1   = (const float*)d_in[2];
    const float* w2   = (const float*)d_in[3];   // dict order: x, gate_w, w1, w2, w3
    const float* w3   = (const float*)d_in[4];
    float* out = (float*)d_out;

    const size_t WB = (size_t)NE * D_FF * D_MODEL * 2;   // 64 MB per weight in bf16
    char* p = (char*)d_ws;
    unsigned short* Wb1 = (unsigned short*)p;  p += WB;
    unsigned short* Wb3 = (unsigned short*)p;  p += WB;
    unsigned short* Wb2 = (unsigned short*)p;  p += WB;
    unsigned short* Xg  = (unsigned short*)p;  p += (size_t)RTOT * D_MODEL * 2;
    unsigned short* H   = (unsigned short*)p;  p += (size_t)RTOT * D_FF * 2;
    int*   e0a = (int*)p;    p += NTOK * 4;
    int*   e1a = (int*)p;    p += NTOK * 4;
    float* w0a = (float*)p;  p += NTOK * 4;
    float* w1a = (float*)p;  p += NTOK * 4;
    int*   tok = (int*)p;    p += RTOT * 4;
    float* wl  = (float*)p;  p += RTOT * 4;
    int*   M   = (int*)p;    p += 64;
    int*   counts = (int*)p; p += 64;
    float* probsum = (float*)p; p += 64;

    hipMemsetAsync(d_out, 0, (size_t)out_size * 4, stream);
    hipMemsetAsync(probsum, 0, NE * sizeof(float), stream);

    int n4 = NE * D_FF * D_MODEL / 4;
    cvt_kernel<<<2048, 256, 0, stream>>>(w1, Wb1, n4);
    cvt_kernel<<<2048, 256, 0, stream>>>(w3, Wb3, n4);
    cvt_kernel<<<2048, 256, 0, stream>>>(w2, Wb2, n4);

    router_kernel<<<NTOK / 4, 256, 0, stream>>>(x, gate, e0a, e1a, w0a, w1a, probsum);
    scan_kernel<<<1, 512, 0, stream>>>(e0a, e1a, w0a, w1a, tok, wl, M, counts);
    gather_kernel<<<RTOT / 4, 256, 0, stream>>>(x, tok, M, Xg);

    gemm1_kernel<<<NE * 20 * 32, 256, 0, stream>>>(Xg, Wb1, Wb3, H);
    gemm2_kernel<<<NE * 20 * 8, 256, 0, stream>>>(H, Wb2, tok, wl, M, out);

    aux_kernel<<<1, 64, 0, stream>>>(counts, probsum, out + (size_t)NTOK * D_MODEL);
}

// Round 2
// 1606.224 us; speedup vs baseline: 1.4877x; 1.4877x over previous
//
#include <hip/hip_runtime.h>
#include <stdint.h>

#define D_MODEL 1024
#define D_FF    4096
#define NE      8
#define NTOK    8192
#define CAP     1280
#define RPE     2560           // rows per expert = 2*CAP (k=0 segment + k=1 segment)
#define RTOT    (NE*RPE)       // 20480
#define TM      128
#define TN      128
#define BK      64
#define SK      (BK+8)         // LDS row stride (+16B pad -> bank stride 4 -> <=2-way, free)
#define RBLK    (NTOK/4)       // router blocks (4 tokens per block)

typedef __attribute__((ext_vector_type(8))) short s8v;   // 8 x bf16 bits (4 VGPRs)
typedef __attribute__((ext_vector_type(4))) float f4v;   // MFMA accumulator

// fp32 -> bf16 round-to-nearest-even (finite inputs only)
__device__ inline unsigned short f2bf(float f) {
    unsigned int u = __float_as_uint(f);
    u += 0x7fffu + ((u >> 16) & 1u);
    return (unsigned short)(u >> 16);
}

// ---------------- weight fp32 -> bf16 conversion ----------------
__global__ __launch_bounds__(256) void cvt_kernel(const float* __restrict__ src,
                                                  unsigned short* __restrict__ dst, int n4) {
    int i = blockIdx.x * blockDim.x + threadIdx.x;
    int stride = gridDim.x * blockDim.x;
    for (; i < n4; i += stride) {
        float4 v = ((const float4*)src)[i];
        union { unsigned short us[4]; uint2 u2; } cv;
        cv.us[0] = f2bf(v.x); cv.us[1] = f2bf(v.y);
        cv.us[2] = f2bf(v.z); cv.us[3] = f2bf(v.w);
        ((uint2*)dst)[i] = cv.u2;
    }
}

// ---------------- router: fp64 logits, top-2, per-block prob partials ----------------
__global__ __launch_bounds__(256) void router_kernel(const float* __restrict__ x,
                                                     const float* __restrict__ gate,
                                                     int* __restrict__ e0a, int* __restrict__ e1a,
                                                     float* __restrict__ w0a, float* __restrict__ w1a,
                                                     float* __restrict__ partial) {
    __shared__ float gs[NE * D_MODEL];   // 32 KB
    __shared__ float ps[NE];
    int tid = threadIdx.x;
    for (int i = tid; i < NE * D_MODEL; i += 256) gs[i] = gate[i];
    if (tid < NE) ps[tid] = 0.0f;
    __syncthreads();
    int wv = tid >> 6, lane = tid & 63;
    int t = blockIdx.x * 4 + wv;
    const float* xr = x + (size_t)t * D_MODEL;
    double acc[NE];
    #pragma unroll
    for (int e = 0; e < NE; e++) acc[e] = 0.0;
    #pragma unroll
    for (int j = 0; j < 16; j++) {
        int d = lane + 64 * j;
        double xv = (double)xr[d];
        #pragma unroll
        for (int e = 0; e < NE; e++) acc[e] += xv * (double)gs[e * D_MODEL + d];
    }
    #pragma unroll
    for (int e = 0; e < NE; e++) {
        #pragma unroll
        for (int off = 32; off > 0; off >>= 1) acc[e] += __shfl_xor(acc[e], off);
    }
    if (lane == 0) {
        double mx = acc[0];
        #pragma unroll
        for (int e = 1; e < NE; e++) mx = fmax(mx, acc[e]);
        double p[NE], s = 0.0;
        #pragma unroll
        for (int e = 0; e < NE; e++) { p[e] = exp(acc[e] - mx); s += p[e]; }
        float p32[NE];
        #pragma unroll
        for (int e = 0; e < NE; e++) p32[e] = (float)(p[e] / s);
        int b0 = 0;
        #pragma unroll
        for (int e = 1; e < NE; e++) if (p32[e] > p32[b0]) b0 = e;   // strict > => lowest idx on tie
        int b1 = (b0 == 0) ? 1 : 0;
        #pragma unroll
        for (int e = 0; e < NE; e++) if (e != b0 && p32[e] > p32[b1]) b1 = e;
        float denom = p32[b0] + p32[b1] + 1e-10f;
        e0a[t] = b0; e1a[t] = b1;
        w0a[t] = p32[b0] / denom;
        w1a[t] = p32[b1] / denom;
        #pragma unroll
        for (int e = 0; e < NE; e++) atomicAdd(&ps[e], p32[e]);   // LDS atomic: 32/block, cheap
    }
    __syncthreads();
    if (tid < NE) partial[blockIdx.x * NE + tid] = ps[tid];
}

// ---------------- per-expert ordered capacity scan ----------------
__global__ __launch_bounds__(512) void scan_kernel(const int* __restrict__ e0a, const int* __restrict__ e1a,
                                                   const float* __restrict__ w0a, const float* __restrict__ w1a,
                                                   int* __restrict__ tok, float* __restrict__ wl,
                                                   int* __restrict__ M, int* __restrict__ counts) {
    int e = threadIdx.x >> 6;       // 8 waves, one per expert
    int lane = threadIdx.x & 63;
    unsigned long long below = (1ull << lane) - 1ull;
    int c = 0;
    for (int base = 0; base < NTOK; base += 64) {          // k = 0
        int t = base + lane;
        bool m = (e0a[t] == e);
        unsigned long long mask = __ballot(m);
        int pos = c + __popcll(mask & below);
        if (m && pos < CAP) { tok[e * RPE + pos] = t; wl[e * RPE + pos] = w0a[t]; }
        c += __popcll(mask);
    }
    int c0 = c;
    int base0 = (c0 < CAP) ? c0 : CAP;
    c = 0;
    for (int base = 0; base < NTOK; base += 64) {          // k = 1
        int t = base + lane;
        bool m = (e1a[t] == e);
        unsigned long long mask = __ballot(m);
        int pos = c + __popcll(mask & below);
        if (m && pos < CAP) { tok[e * RPE + base0 + pos] = t; wl[e * RPE + base0 + pos] = w1a[t]; }
        c += __popcll(mask);
    }
    int c1 = c;
    if (lane == 0) {
        M[e] = base0 + ((c1 < CAP) ? c1 : CAP);
        counts[e] = c0 + c1;          // pre-capacity counts, per reference
    }
}

// ---------------- gather x rows -> zero-padded bf16 buffer ----------------
__global__ __launch_bounds__(256) void gather_kernel(const float* __restrict__ x,
                                                     const int* __restrict__ tok,
                                                     const int* __restrict__ M,
                                                     unsigned short* __restrict__ Xg) {
    int wv = threadIdx.x >> 6, lane = threadIdx.x & 63;
    int r = blockIdx.x * 4 + wv;              // 0..RTOT-1
    int e = r / RPE;
    int i = r - e * RPE;
    unsigned short* dst = Xg + (size_t)r * D_MODEL;
    if (i < M[e]) {
        int t = tok[r];
        const float4* src = (const float4*)(x + (size_t)t * D_MODEL);
        #pragma unroll
        for (int j = 0; j < 4; j++) {
            float4 v = src[lane + 64 * j];
            union { unsigned short us[4]; uint2 u2; } cv;
            cv.us[0] = f2bf(v.x); cv.us[1] = f2bf(v.y);
            cv.us[2] = f2bf(v.z); cv.us[3] = f2bf(v.w);
            *(uint2*)(dst + (size_t)(lane + 64 * j) * 4) = cv.u2;
        }
    } else {
        uint2 z; z.x = 0u; z.y = 0u;
        #pragma unroll
        for (int j = 0; j < 4; j++) *(uint2*)(dst + (size_t)(lane + 64 * j) * 4) = z;
    }
}

// ---------------- GEMM1: H = silu(Xg W1^T) * (Xg W3^T), bf16 out ----------------
__global__ __launch_bounds__(256) void gemm1_kernel(const unsigned short* __restrict__ Xg,
                                                    const unsigned short* __restrict__ Wb1,
                                                    const unsigned short* __restrict__ Wb3,
                                                    unsigned short* __restrict__ H) {
    __shared__ __align__(16) unsigned short As[TM * SK];
    __shared__ __align__(16) unsigned short B1s[TN * SK];
    __shared__ __align__(16) unsigned short B3s[TN * SK];
    int bx = blockIdx.x;
    int e = bx / 640;                 // 640 = 32 n-tiles * 20 m-tiles
    int r = bx - e * 640;
    int nt = r / 20;                  // mt fastest: B-strips shared by consecutive blocks
    int mt = r - nt * 20;
    const unsigned short* Ab = Xg + ((size_t)e * RPE + (size_t)mt * TM) * D_MODEL;
    const unsigned short* B1b = Wb1 + (size_t)e * D_FF * D_MODEL + (size_t)nt * TN * D_MODEL;
    const unsigned short* B3b = Wb3 + (size_t)e * D_FF * D_MODEL + (size_t)nt * TN * D_MODEL;
    int tid = threadIdx.x;
    int lane = tid & 63, wv = tid >> 6;
    int wm = wv & 1, wn = wv >> 1;
    int quad = lane >> 4, l16 = lane & 15;
    f4v acc1[4][4], acc3[4][4];
    #pragma unroll
    for (int i = 0; i < 4; i++)
        #pragma unroll
        for (int j = 0; j < 4; j++) { acc1[i][j] = 0.0f; acc3[i][j] = 0.0f; }

    for (int kt = 0; kt < D_MODEL / BK; kt++) {
        int kof = kt * BK;
        s8v va[4], v1[4], v3[4];
        #pragma unroll
        for (int c = 0; c < 4; c++) {
            int chunk = c * 256 + tid;
            int row = chunk >> 3;
            int col = (chunk & 7) * 8;
            va[c] = *(const s8v*)(Ab  + (size_t)row * D_MODEL + kof + col);
            v1[c] = *(const s8v*)(B1b + (size_t)row * D_MODEL + kof + col);
            v3[c] = *(const s8v*)(B3b + (size_t)row * D_MODEL + kof + col);
        }
        __syncthreads();
        #pragma unroll
        for (int c = 0; c < 4; c++) {
            int chunk = c * 256 + tid;
            int row = chunk >> 3;
            int col = (chunk & 7) * 8;
            *(s8v*)(As  + row * SK + col) = va[c];
            *(s8v*)(B1s + row * SK + col) = v1[c];
            *(s8v*)(B3s + row * SK + col) = v3[c];
        }
        __syncthreads();
        #pragma unroll
        for (int st = 0; st < 2; st++) {
            s8v af[4], bf1[4], bf3[4];
            #pragma unroll
            for (int i = 0; i < 4; i++)
                af[i] = *(const s8v*)(As + (wm * 64 + i * 16 + l16) * SK + st * 32 + quad * 8);
            #pragma unroll
            for (int j = 0; j < 4; j++) {
                bf1[j] = *(const s8v*)(B1s + (wn * 64 + j * 16 + l16) * SK + st * 32 + quad * 8);
                bf3[j] = *(const s8v*)(B3s + (wn * 64 + j * 16 + l16) * SK + st * 32 + quad * 8);
            }
            #pragma unroll
            for (int i = 0; i < 4; i++)
                #pragma unroll
                for (int j = 0; j < 4; j++) {
                    acc1[i][j] = __builtin_amdgcn_mfma_f32_16x16x32_bf16(af[i], bf1[j], acc1[i][j], 0, 0, 0);
                    acc3[i][j] = __builtin_amdgcn_mfma_f32_16x16x32_bf16(af[i], bf3[j], acc3[i][j], 0, 0, 0);
                }
        }
    }
    size_t rowbase = (size_t)e * RPE + (size_t)mt * TM;
    #pragma unroll
    for (int i = 0; i < 4; i++) {
        #pragma unroll
        for (int j = 0; j < 4; j++) {
            int col = nt * TN + wn * 64 + j * 16 + l16;
            #pragma unroll
            for (int rg = 0; rg < 4; rg++) {
                int row = wm * 64 + i * 16 + quad * 4 + rg;   // C/D: col=lane&15, row=quad*4+reg
                float z = acc1[i][j][rg];
                float sg = z / (1.0f + __expf(-z));           // silu
                float h = sg * acc3[i][j][rg];
                H[(rowbase + row) * (size_t)D_FF + col] = f2bf(h);
            }
        }
    }
}

// ---------------- GEMM2: OUT = H W2^T, weighted scatter-add ----------------
__global__ __launch_bounds__(256) void gemm2_kernel(const unsigned short* __restrict__ H,
                                                    const unsigned short* __restrict__ Wb2,
                                                    const int* __restrict__ tok,
                                                    const float* __restrict__ wl,
                                                    const int* __restrict__ M,
                                                    float* __restrict__ out) {
    __shared__ __align__(16) unsigned short As[TM * SK];
    __shared__ __align__(16) unsigned short Bs[TN * SK];
    __shared__ int   tok_s[TM];
    __shared__ float wl_s[TM];
    int bx = blockIdx.x;
    int e = bx / 160;                 // 160 = 20 m-tiles * 8 n-tiles
    int r = bx - e * 160;
    int mt = r >> 3;                  // nt fastest: A-tile shared by consecutive blocks
    int nt = r & 7;
    const unsigned short* Ab = H + ((size_t)e * RPE + (size_t)mt * TM) * D_FF;
    const unsigned short* Bb = Wb2 + (size_t)e * D_MODEL * D_FF + (size_t)nt * TN * D_FF;
    int tid = threadIdx.x;
    if (tid < TM) {
        tok_s[tid] = tok[e * RPE + mt * TM + tid];
        wl_s[tid]  = wl[e * RPE + mt * TM + tid];
    }
    int Me = M[e];
    int lane = tid & 63, wv = tid >> 6;
    int wm = wv & 1, wn = wv >> 1;
    int quad = lane >> 4, l16 = lane & 15;
    f4v acc[4][4];
    #pragma unroll
    for (int i = 0; i < 4; i++)
        #pragma unroll
        for (int j = 0; j < 4; j++) acc[i][j] = 0.0f;

    for (int kt = 0; kt < D_FF / BK; kt++) {
        int kof = kt * BK;
        s8v va[4], vb[4];
        #pragma unroll
        for (int c = 0; c < 4; c++) {
            int chunk = c * 256 + tid;
            int row = chunk >> 3;
            int col = (chunk & 7) * 8;
            va[c] = *(const s8v*)(Ab + (size_t)row * D_FF + kof + col);
            vb[c] = *(const s8v*)(Bb + (size_t)row * D_FF + kof + col);
        }
        __syncthreads();
        #pragma unroll
        for (int c = 0; c < 4; c++) {
            int chunk = c * 256 + tid;
            int row = chunk >> 3;
            int col = (chunk & 7) * 8;
            *(s8v*)(As + row * SK + col) = va[c];
            *(s8v*)(Bs + row * SK + col) = vb[c];
        }
        __syncthreads();
        #pragma unroll
        for (int st = 0; st < 2; st++) {
            s8v af[4], bf[4];
            #pragma unroll
            for (int i = 0; i < 4; i++)
                af[i] = *(const s8v*)(As + (wm * 64 + i * 16 + l16) * SK + st * 32 + quad * 8);
            #pragma unroll
            for (int j = 0; j < 4; j++)
                bf[j] = *(const s8v*)(Bs + (wn * 64 + j * 16 + l16) * SK + st * 32 + quad * 8);
            #pragma unroll
            for (int i = 0; i < 4; i++)
                #pragma unroll
                for (int j = 0; j < 4; j++)
                    acc[i][j] = __builtin_amdgcn_mfma_f32_16x16x32_bf16(af[i], bf[j], acc[i][j], 0, 0, 0);
        }
    }
    int mbase = mt * TM;
    #pragma unroll
    for (int i = 0; i < 4; i++) {
        #pragma unroll
        for (int j = 0; j < 4; j++) {
            int col = nt * TN + wn * 64 + j * 16 + l16;
            #pragma unroll
            for (int rg = 0; rg < 4; rg++) {
                int row = wm * 64 + i * 16 + quad * 4 + rg;
                if (mbase + row < Me) {
                    float v = acc[i][j][rg] * wl_s[row];
                    atomicAdd(out + (size_t)tok_s[row] * D_MODEL + col, v);
                }
            }
        }
    }
}

// ---------------- aux loss finisher: reduce per-block prob partials ----------------
__global__ __launch_bounds__(64) void aux_kernel(const int* __restrict__ counts,
                                                 const float* __restrict__ partial,
                                                 float* __restrict__ out_aux) {
    __shared__ float red[64];
    int tid = threadIdx.x;
    int e = tid & 7;            // expert
    int chunk = tid >> 3;       // 8 chunks of 256 blocks
    float s = 0.0f;
    for (int b = chunk * (RBLK / 8); b < (chunk + 1) * (RBLK / 8); b++)
        s += partial[b * NE + e];
    red[tid] = s;
    __syncthreads();
    if (tid == 0) {
        float total = 0.0f;
        for (int e2 = 0; e2 < NE; e2++) {
            float P = 0.0f;
            for (int c = 0; c < 8; c++) P += red[c * 8 + e2];
            P /= (float)NTOK;
            float f = (float)counts[e2] / (float)(NTOK * 2);
            total += f * P;
        }
        *out_aux = (float)NE * total;
    }
}

extern "C" void kernel_launch(void* const* d_in, const int* in_sizes, int n_in,
                              void* d_out, int out_size, void* d_ws, size_t ws_size,
                              hipStream_t stream) {
    (void)in_sizes; (void)n_in; (void)ws_size;
    const float* x    = (const float*)d_in[0];
    const float* gate = (const float*)d_in[1];
    const float* w1   = (const float*)d_in[2];
    const float* w2   = (const float*)d_in[3];   // dict order: x, gate_w, w1, w2, w3
    const float* w3   = (const float*)d_in[4];
    float* out = (float*)d_out;

    const size_t WB = (size_t)NE * D_FF * D_MODEL * 2;   // 64 MB per weight in bf16
    char* p = (char*)d_ws;
    unsigned short* Wb1 = (unsigned short*)p;  p += WB;
    unsigned short* Wb3 = (unsigned short*)p;  p += WB;
    unsigned short* Wb2 = (unsigned short*)p;  p += WB;
    unsigned short* Xg  = (unsigned short*)p;  p += (size_t)RTOT * D_MODEL * 2;
    unsigned short* H   = (unsigned short*)p;  p += (size_t)RTOT * D_FF * 2;
    int*   e0a = (int*)p;    p += NTOK * 4;
    int*   e1a = (int*)p;    p += NTOK * 4;
    float* w0a = (float*)p;  p += NTOK * 4;
    float* w1a = (float*)p;  p += NTOK * 4;
    int*   tok = (int*)p;    p += RTOT * 4;
    float* wl  = (float*)p;  p += RTOT * 4;
    int*   M   = (int*)p;    p += 64;
    int*   counts = (int*)p; p += 64;
    float* partial = (float*)p; p += RBLK * NE * 4;   // 2048*8 floats

    hipMemsetAsync(d_out, 0, (size_t)out_size * 4, stream);

    int n4 = NE * D_FF * D_MODEL / 4;
    cvt_kernel<<<2048, 256, 0, stream>>>(w1, Wb1, n4);
    cvt_kernel<<<2048, 256, 0, stream>>>(w3, Wb3, n4);
    cvt_kernel<<<2048, 256, 0, stream>>>(w2, Wb2, n4);

    router_kernel<<<RBLK, 256, 0, stream>>>(x, gate, e0a, e1a, w0a, w1a, partial);
    scan_kernel<<<1, 512, 0, stream>>>(e0a, e1a, w0a, w1a, tok, wl, M, counts);
    gather_kernel<<<RTOT / 4, 256, 0, stream>>>(x, tok, M, Xg);

    gemm1_kernel<<<NE * 20 * 32, 256, 0, stream>>>(Xg, Wb1, Wb3, H);
    gemm2_kernel<<<NE * 20 * 8, 256, 0, stream>>>(H, Wb2, tok, wl, M, out);

    aux_kernel<<<1, 64, 0, stream>>>(counts, partial, out + (size_t)NTOK * D_MODEL);
}